// Round 1
// baseline (836.283 us; speedup 1.0000x reference)
//
#include <hip/hip_runtime.h>
#include <hip/hip_bf16.h>
#include <hip/hip_fp8.h>

// ---------------------------------------------------------------------------
// GRACE contrastive loss, MI355X.
//  out = mean_k 0.5*(ln d1_k + ln d2_k) - 2*s12[k,k]
// With M=[n1;n2] (24576x256) everything is row sums of exp(M M^T / tau)
// split by j-half, plus diagonal probes.
//
// R7: occupancy fix for sim. R6 had 2x32KB LDS -> 2 blocks/CU -> 2 waves/SIMD
// barrier-locked together; MfmaUtil 41% = 66us MFMA floor / 167us. Trans+VALU
// (exp2 epilogue) is ~40us/SIMD < 66us MFMA, so it hides IF independent waves
// coexist. New geometry: BMS=256 rows/block, BJS=64 cols/jt => Bs 2x16KB,
// grid 768 = exactly 3 co-resident blocks/CU (12 waves/CU, unsynced phases).
// Wave = 64 rows x 64 cols (aF 64 VGPR unchanged), 48 jt double-buffered,
// one barrier per jt. Also: finalize split into 48-block partial + combine
// (was 1 latency-bound block), 4 cast launches merged into 1.
// ---------------------------------------------------------------------------

#define NROWS 12288
#define TWO_N 24576
#define KDIM 256
#define BM 128
#define BN 128
#define BK 32
#define NCHUNK 8
#define JCHUNK (TWO_N / NCHUNK) /* 3072 */
#define BMS 256                 /* sim rows per block */
#define BJS 64                  /* sim cols per jt tile */
#define JTILES_S (JCHUNK / BJS) /* 48 */
#define FB 48                   /* finalize partial blocks */
#define LOG2E 1.4426950408889634f
#define SIMSCALE 1.6986436f     /* sqrt(2*log2(e)); acc = (1/tau)*log2e*s */
#define LN2F 0.6931471805599453f

#if __has_builtin(__builtin_amdgcn_exp2f)
#define EXP2F(x) __builtin_amdgcn_exp2f(x)
#else
#define EXP2F(x) exp2f(x)
#endif

typedef __bf16 bf16x8 __attribute__((ext_vector_type(8)));
typedef __bf16 bf16x4v __attribute__((ext_vector_type(4)));
typedef float f32x4 __attribute__((ext_vector_type(4)));
typedef int i32x4 __attribute__((ext_vector_type(4)));
typedef int i32x8 __attribute__((ext_vector_type(8)));
typedef unsigned char uchar;

typedef const __attribute__((address_space(1))) void* gptr_t;
typedef __attribute__((address_space(3))) void* lptr_t;

// ======== legacy 128x128 bf16 GEMM core (proj1/proj2 only) ================
__device__ __forceinline__ void stage_slab(const __bf16* g, int row0, int kelem,
                                           __bf16* lds, int w, int l) {
#pragma unroll
  for (int t = 0; t < 2; ++t) {
    int chunk = w * 2 + t;
    int r = chunk * 16 + (l >> 2);
    int c = l & 3;
    int src = c ^ (r & 3);
    const __bf16* ga = g + (size_t)(row0 + r) * KDIM + kelem + src * 8;
    __bf16* la = lds + chunk * 512;
    __builtin_amdgcn_global_load_lds((gptr_t)ga, (lptr_t)la, 16, 0, 0);
  }
}

__device__ __forceinline__ bf16x8 read_frag(const __bf16* lds, int rowbase,
                                            int tile, int l) {
  int r = rowbase + tile * 16 + (l & 15);
  int q = l >> 4;
  int blk = q ^ (r & 3);
  return *(const bf16x8*)(lds + r * 32 + blk * 8);
}

__device__ __forceinline__ void gemm_tile_core(const __bf16* A, int arow0,
                                               const __bf16* B, int brow0,
                                               __bf16* As, __bf16* Bs,
                                               f32x4 (&acc)[4][4], int w, int l) {
  const int warow = (w >> 1) * 64;
  const int wbrow = (w & 1) * 64;
#pragma unroll
  for (int ks = 0; ks < KDIM / BK; ++ks) {
    __syncthreads();
    stage_slab(A, arow0, ks * BK, As, w, l);
    stage_slab(B, brow0, ks * BK, Bs, w, l);
    __syncthreads();
    bf16x8 aF[4], bF[4];
#pragma unroll
    for (int mi = 0; mi < 4; ++mi) aF[mi] = read_frag(As, warow, mi, l);
#pragma unroll
    for (int ni = 0; ni < 4; ++ni) bF[ni] = read_frag(Bs, wbrow, ni, l);
#pragma unroll
    for (int mi = 0; mi < 4; ++mi)
#pragma unroll
      for (int ni = 0; ni < 4; ++ni)
        acc[mi][ni] = __builtin_amdgcn_mfma_f32_16x16x32_bf16(
            aF[mi], bF[ni], acc[mi][ni], 0, 0, 0);
  }
}

// ---------------------------------------------------------------------------
// one launch: cast z1, z2, W1, W2 to bf16 (float4 granules)
__global__ void cast_all_kernel(const float* __restrict__ z1,
                                const float* __restrict__ z2,
                                const float* __restrict__ W1,
                                const float* __restrict__ W2,
                                __bf16* __restrict__ Zb,
                                __bf16* __restrict__ W1b,
                                __bf16* __restrict__ W2b) {
  const int n4z = NROWS * KDIM / 4;  // 786432
  const int n4w = KDIM * KDIM / 4;   // 16384
  int i = blockIdx.x * blockDim.x + threadIdx.x;
  const float* src;
  __bf16* dst;
  int j;
  if (i < n4z) {
    src = z1; dst = Zb; j = i;
  } else if (i < 2 * n4z) {
    src = z2; dst = Zb + (size_t)NROWS * KDIM; j = i - n4z;
  } else if (i < 2 * n4z + n4w) {
    src = W1; dst = W1b; j = i - 2 * n4z;
  } else if (i < 2 * n4z + 2 * n4w) {
    src = W2; dst = W2b; j = i - 2 * n4z - n4w;
  } else {
    return;
  }
  float4 v = *(const float4*)(src + (size_t)j * 4);
  bf16x4v o;
  o[0] = (__bf16)v.x; o[1] = (__bf16)v.y; o[2] = (__bf16)v.z; o[3] = (__bf16)v.w;
  *(bf16x4v*)(dst + (size_t)j * 4) = o;
}

// T = ELU(Z @ W1^T + b1), stored bf16
__global__ __launch_bounds__(256, 2) void proj1_kernel(
    const __bf16* __restrict__ Zb, const __bf16* __restrict__ W1b,
    const float* __restrict__ b1, __bf16* __restrict__ Tb) {
  __shared__ __align__(16) __bf16 As[BM * BK];
  __shared__ __align__(16) __bf16 Bs[BN * BK];
  int w = threadIdx.x >> 6, l = threadIdx.x & 63;
  int i0 = blockIdx.x * BM, j0 = blockIdx.y * BN;
  int warow = (w >> 1) * 64, wbrow = (w & 1) * 64;
  f32x4 acc[4][4] = {};
  gemm_tile_core(Zb, i0, W1b, j0, As, Bs, acc, w, l);
  float bias[4];
#pragma unroll
  for (int ni = 0; ni < 4; ++ni) bias[ni] = b1[j0 + wbrow + ni * 16 + (l & 15)];
#pragma unroll
  for (int mi = 0; mi < 4; ++mi)
#pragma unroll
    for (int ni = 0; ni < 4; ++ni)
#pragma unroll
      for (int v = 0; v < 4; ++v) {
        int row = i0 + warow + mi * 16 + (l >> 4) * 4 + v;
        int col = j0 + wbrow + ni * 16 + (l & 15);
        float x = acc[mi][ni][v] + bias[ni];
        x = x > 0.f ? x : (EXP2F(x * LOG2E) - 1.f);  // ELU
        Tb[(size_t)row * KDIM + col] = (__bf16)x;
      }
}

// H = T @ W2^T + b2 (fp32), plus per-row sum of squares via atomics
__global__ __launch_bounds__(256, 2) void proj2_kernel(
    const __bf16* __restrict__ Tb, const __bf16* __restrict__ W2b,
    const float* __restrict__ b2, float* __restrict__ H,
    float* __restrict__ SS) {
  __shared__ __align__(16) __bf16 As[BM * BK];
  __shared__ __align__(16) __bf16 Bs[BN * BK];
  int w = threadIdx.x >> 6, l = threadIdx.x & 63;
  int i0 = blockIdx.x * BM, j0 = blockIdx.y * BN;
  int warow = (w >> 1) * 64, wbrow = (w & 1) * 64;
  f32x4 acc[4][4] = {};
  gemm_tile_core(Tb, i0, W2b, j0, As, Bs, acc, w, l);
  float bias[4];
#pragma unroll
  for (int ni = 0; ni < 4; ++ni) bias[ni] = b2[j0 + wbrow + ni * 16 + (l & 15)];
  float ss[4][4] = {};
#pragma unroll
  for (int mi = 0; mi < 4; ++mi)
#pragma unroll
    for (int ni = 0; ni < 4; ++ni)
#pragma unroll
      for (int v = 0; v < 4; ++v) {
        int row = i0 + warow + mi * 16 + (l >> 4) * 4 + v;
        int col = j0 + wbrow + ni * 16 + (l & 15);
        float x = acc[mi][ni][v] + bias[ni];
        H[(size_t)row * KDIM + col] = x;
        ss[mi][v] += x * x;
      }
#pragma unroll
  for (int mi = 0; mi < 4; ++mi)
#pragma unroll
    for (int v = 0; v < 4; ++v) {
      float x = ss[mi][v];
      x += __shfl_xor(x, 1, 64);
      x += __shfl_xor(x, 2, 64);
      x += __shfl_xor(x, 4, 64);
      x += __shfl_xor(x, 8, 64);
      if ((l & 15) == 0)
        atomicAdd(&SS[i0 + warow + mi * 16 + (l >> 4) * 4 + v], x);
    }
}

// pack 4 floats -> 4 fp8 e4m3 bytes
__device__ __forceinline__ unsigned int pack4_fp8(float a, float b, float c,
                                                  float d) {
#if __has_builtin(__builtin_amdgcn_cvt_pk_fp8_f32)
  int v = 0;
  v = __builtin_amdgcn_cvt_pk_fp8_f32(a, b, v, false);
  v = __builtin_amdgcn_cvt_pk_fp8_f32(c, d, v, true);
  return (unsigned int)v;
#else
  __hip_fp8_e4m3 qa(a), qb(b), qc(c), qd(d);
  return (unsigned int)qa.__x | ((unsigned int)qb.__x << 8) |
         ((unsigned int)qc.__x << 16) | ((unsigned int)qd.__x << 24);
#endif
}

// Nq = fp8(H * rsqrt(SS[row]) * SIMSCALE) — 8 elements per thread.
// SIMSCALE folds the (1/tau)*log2(e) exponent scale into the data:
// dot(Nq_i, Nq_j) = 2.8854 * cos_ij, so exp2(acc) = exp(cos/tau).
__global__ void norm_kernel(const float* __restrict__ H,
                            const float* __restrict__ SS,
                            uchar* __restrict__ Nq) {
  int i = blockIdx.x * blockDim.x + threadIdx.x;
  size_t idx = (size_t)i * 8;
  if (idx >= (size_t)TWO_N * KDIM) return;
  int row = (int)(idx >> 8);
  float inv = rsqrtf(SS[row]) * SIMSCALE;
  float4 h0 = *(const float4*)(H + idx);
  float4 h1 = *(const float4*)(H + idx + 4);
  uint2 o;
  o.x = pack4_fp8(h0.x * inv, h0.y * inv, h0.z * inv, h0.w * inv);
  o.y = pack4_fp8(h1.x * inv, h1.y * inv, h1.z * inv, h1.w * inv);
  *(uint2*)(Nq + idx) = o;
}

// ======== R7 sim kernel (MX-scaled fp8, high-occupancy) ====================
// grid = 768 1D blocks (exactly 3/CU, all co-resident). chunk = blockIdx&7
// (XCD-pinned j-range), itile = blockIdx>>3 (256 A-rows). 4 waves x (64 rows
// x 64 cols). aF 64 VGPRs; acc[4] live per nj step (full-K per nj); jt-level
// LDS double buffer 2x16KB, ONE barrier per jt, stage(jt+1) issued after
// barrier(jt), drains at barrier(jt+1) under 32 MFMAs + exp epilogue.
__global__ __launch_bounds__(256, 4) void sim_kernel(
    const uchar* __restrict__ Nq, float* __restrict__ Rlow,
    float* __restrict__ Rhigh, float* __restrict__ Dsame,
    float* __restrict__ Dcross) {
  __shared__ __align__(16) uchar Bs[2][BJS * KDIM];  // 2 x 16KB
  int tid = threadIdx.x;
  int w = tid >> 6, l = tid & 63;
  int q = l >> 4;
  int b = blockIdx.x;
  int chunk = b & 7;           // XCD id under round-robin dispatch
  int i0 = (b >> 3) * BMS;
  int jbase = chunk * JCHUNK;
  int warow = w * 64;          // this wave owns rows [warow, warow+64)

  // stage full 64-row x 256B tile jt into buffer bi; source-side XOR
  // swizzle: LDS slot c of row r holds global 16B-block c ^ (r&15).
  auto stage = [&](int jt, int bi) {
    int j0 = jbase + jt * BJS;
#pragma unroll
    for (int t = 0; t < 4; ++t) {
      int ch = w * 4 + t;            // wave-uniform chunk 0..15 (1KB each)
      int r = ch * 4 + (l >> 4);     // row 0..63 (4 rows per chunk)
      int c = l & 15;                // dest 16B-block slot
      int src = c ^ (r & 15);        // global k-block landing in slot c
      const uchar* ga = Nq + (size_t)(j0 + r) * KDIM + src * 16;
      uchar* la = Bs[bi] + ch * 1024;  // wave-uniform base
      __builtin_amdgcn_global_load_lds((gptr_t)ga, (lptr_t)la, 16, 0, 0);
    }
  };

  // ---- A fragments in registers: aF[mi][hf], 8 x i32x8 = 64 VGPRs ----
  // f8f6f4 16x16x128 A layout: lane holds row (l&15), k = q*32 + 0..31.
  i32x8 aF[4][2];
#pragma unroll
  for (int mi = 0; mi < 4; ++mi) {
    const uchar* ap =
        Nq + (size_t)(i0 + warow + mi * 16 + (l & 15)) * KDIM + q * 32;
#pragma unroll
    for (int hf = 0; hf < 2; ++hf)
      aF[mi][hf] = *(const i32x8*)(ap + hf * 128);
  }

  float rs[4][4] = {};  // running row sums (per mi, per v)

  stage(0, 0);  // prologue

  for (int jt = 0; jt < JTILES_S; ++jt) {
    int bi = jt & 1;
    __syncthreads();                       // stage(jt) done; prev readers done
    if (jt + 1 < JTILES_S) stage(jt + 1, bi ^ 1);  // drains at NEXT barrier

    int j0 = jbase + jt * BJS;
    // diagonal hits this wave's 64-row band only when col-tile aligns with it
    bool dsame = (j0 == i0 + warow);
    bool dcross = (j0 == i0 + warow + NROWS);

#pragma unroll
    for (int nj = 0; nj < 4; ++nj) {
      int row = nj * 16 + (l & 15);
      const uchar* base = Bs[bi] + row * KDIM;
      f32x4 acc[4] = {};
#pragma unroll
      for (int hf = 0; hf < 2; ++hf) {
        int kb = hf * 8 + 2 * q;                 // even global block index
        i32x4 lo = *(const i32x4*)(base + ((kb ^ (row & 15)) << 4));
        i32x4 hi = *(const i32x4*)(base + (((kb + 1) ^ (row & 15)) << 4));
        i32x8 bF = __builtin_shufflevector(lo, hi, 0, 1, 2, 3, 4, 5, 6, 7);
#pragma unroll
        for (int mi = 0; mi < 4; ++mi)
          acc[mi] = __builtin_amdgcn_mfma_scale_f32_16x16x128_f8f6f4(
              aF[mi][hf], bF, acc[mi], 0, 0, 0, 0x7F7F7F7F, 0, 0x7F7F7F7F);
      }
      // epilogue for this nj: acc = s/tau*log2(e); exp2 directly
#pragma unroll
      for (int mi = 0; mi < 4; ++mi)
#pragma unroll
        for (int v = 0; v < 4; ++v)
          rs[mi][v] += EXP2F(acc[mi][v]);

      if (dsame | dcross) {       // wave-uniform, 2 of 48 jt iterations
        float* D = dsame ? Dsame : Dcross;
#pragma unroll
        for (int mi = 0; mi < 4; ++mi)
#pragma unroll
          for (int v = 0; v < 4; ++v) {
            int li = mi * 16 + q * 4 + v;     // within wave's 64 rows
            int lj = nj * 16 + (l & 15);      // within tile's 64 cols
            if (li == lj) D[i0 + warow + li] = acc[mi][v];
          }
      }
    }
  }

  // cross-lane (16-wide) reduce, one atomicAdd per row per wave
  float* R = (chunk >= NCHUNK / 2) ? Rhigh : Rlow;
#pragma unroll
  for (int mi = 0; mi < 4; ++mi)
#pragma unroll
    for (int v = 0; v < 4; ++v) {
      float x = rs[mi][v];
      x += __shfl_xor(x, 1, 64);
      x += __shfl_xor(x, 2, 64);
      x += __shfl_xor(x, 4, 64);
      x += __shfl_xor(x, 8, 64);
      if ((l & 15) == 0)
        atomicAdd(&R[i0 + warow + mi * 16 + q * 4 + v], x);
    }
}

// Dsame/Dcross hold acc = (1/tau)*log2e * s. exp(s/tau) = exp2(acc);
// -2*s = -ln2 * acc.  48 blocks x 256 threads = 12288 rows exactly.
__global__ void finalize1_kernel(const float* __restrict__ Rlow,
                                 const float* __restrict__ Rhigh,
                                 const float* __restrict__ Dsame,
                                 const float* __restrict__ Dcross,
                                 float* __restrict__ partial) {
  __shared__ float red[256];
  int k = blockIdx.x * 256 + threadIdx.x;
  float d1 = Rlow[k] + Rhigh[k] - EXP2F(Dsame[k]);
  float d2 = Rhigh[NROWS + k] + Rlow[NROWS + k] - EXP2F(Dsame[NROWS + k]);
  float acc = 0.5f * (logf(d1) + logf(d2)) - LN2F * Dcross[k];
  red[threadIdx.x] = acc;
  __syncthreads();
  for (int s = 128; s > 0; s >>= 1) {
    if (threadIdx.x < s) red[threadIdx.x] += red[threadIdx.x + s];
    __syncthreads();
  }
  if (threadIdx.x == 0) partial[blockIdx.x] = red[0];
}

__global__ void finalize2_kernel(const float* __restrict__ partial,
                                 float* __restrict__ out) {
  float x = (threadIdx.x < FB) ? partial[threadIdx.x] : 0.f;
#pragma unroll
  for (int s = 32; s > 0; s >>= 1) x += __shfl_down(x, s, 64);
  if (threadIdx.x == 0) out[0] = x / (float)NROWS;
}

// ---------------------------------------------------------------------------
extern "C" void kernel_launch(void* const* d_in, const int* in_sizes, int n_in,
                              void* d_out, int out_size, void* d_ws,
                              size_t ws_size, hipStream_t stream) {
  const float* z1 = (const float*)d_in[0];
  const float* z2 = (const float*)d_in[1];
  const float* W1 = (const float*)d_in[2];
  const float* b1 = (const float*)d_in[3];
  const float* W2 = (const float*)d_in[4];
  const float* b2 = (const float*)d_in[5];
  float* out = (float*)d_out;

  char* ws = (char*)d_ws;
  size_t off = 0;
  auto alloc = [&](size_t bytes) -> void* {
    void* p = ws + off;
    off += (bytes + 255) & ~(size_t)255;
    return p;
  };
  __bf16* Zb   = (__bf16*)alloc((size_t)TWO_N * KDIM * 2); // reused as Nq
  __bf16* W1b  = (__bf16*)alloc((size_t)KDIM * KDIM * 2);
  __bf16* W2b  = (__bf16*)alloc((size_t)KDIM * KDIM * 2);
  __bf16* Tb   = (__bf16*)alloc((size_t)TWO_N * KDIM * 2);
  float*  H    = (float*)alloc((size_t)TWO_N * KDIM * 4);
  float*  SS   = (float*)alloc((size_t)TWO_N * 4);
  float*  Rlow = (float*)alloc((size_t)TWO_N * 4);
  float*  Rhigh= (float*)alloc((size_t)TWO_N * 4);
  float*  Dsame= (float*)alloc((size_t)TWO_N * 4);
  float*  Dcross=(float*)alloc((size_t)NROWS * 4);
  float*  partial=(float*)alloc((size_t)FB * 4);
  uchar*  Nq = (uchar*)Zb;  // Zb dead after proj1; fp8 fits in its footprint

  hipMemsetAsync(SS, 0, (size_t)TWO_N * 4, stream);
  hipMemsetAsync(Rlow, 0, (size_t)TWO_N * 4, stream);
  hipMemsetAsync(Rhigh, 0, (size_t)TWO_N * 4, stream);

  int n4z = NROWS * KDIM / 4;   // 786432
  int n4w = KDIM * KDIM / 4;    // 16384
  int n4all = 2 * n4z + 2 * n4w;
  cast_all_kernel<<<(n4all + 255) / 256, 256, 0, stream>>>(z1, z2, W1, W2, Zb,
                                                           W1b, W2b);

  proj1_kernel<<<dim3(TWO_N / BM, KDIM / BN), 256, 0, stream>>>(Zb, W1b, b1, Tb);
  proj2_kernel<<<dim3(TWO_N / BM, KDIM / BN), 256, 0, stream>>>(Tb, W2b, b2, H, SS);

  int n8n = TWO_N * KDIM / 8;   // 786432
  norm_kernel<<<(n8n + 255) / 256, 256, 0, stream>>>(H, SS, Nq);

  sim_kernel<<<(TWO_N / BMS) * NCHUNK, 256, 0, stream>>>(Nq, Rlow, Rhigh,
                                                         Dsame, Dcross);
  finalize1_kernel<<<FB, 256, 0, stream>>>(Rlow, Rhigh, Dsame, Dcross, partial);
  finalize2_kernel<<<1, 64, 0, stream>>>(partial, out);
}

// Round 2
// 285.194 us; speedup vs baseline: 2.9323x; 2.9323x over previous
//
#include <hip/hip_runtime.h>
#include <hip/hip_bf16.h>
#include <hip/hip_fp8.h>

// ---------------------------------------------------------------------------
// GRACE contrastive loss, MI355X.
//  out = mean_k 0.5*(ln d1_k + ln d2_k) - 2*s12[k,k]
// With M=[n1;n2] (24576x256) everything is row sums of exp(M M^T / tau)
// split by j-half, plus diagonal probes.
//
// R8: fix R7's register spill. launch_bounds(256,4) capped the unified
// VGPR budget at 128/wave; gfx950's arch/acc split left 64 arch VGPRs and
// the compiler spilled aF[4][2] (64 VGPRs) to scratch -> FETCH 24.6MB->1.5GB,
// WRITE 6.3->63MB, MfmaUtil 8%, 764us. Geometry was right (2x16KB LDS,
// grid 768 = 3 blocks/CU, 4 waves x 64rows x 64cols); only the cap was
// wrong. (256,3) -> ~170-reg cap, ~130 needed, no spill, 3 blocks/CU as
// designed. Everything else identical to R7 to isolate the spill fix.
// ---------------------------------------------------------------------------

#define NROWS 12288
#define TWO_N 24576
#define KDIM 256
#define BM 128
#define BN 128
#define BK 32
#define NCHUNK 8
#define JCHUNK (TWO_N / NCHUNK) /* 3072 */
#define BMS 256                 /* sim rows per block */
#define BJS 64                  /* sim cols per jt tile */
#define JTILES_S (JCHUNK / BJS) /* 48 */
#define FB 48                   /* finalize partial blocks */
#define LOG2E 1.4426950408889634f
#define SIMSCALE 1.6986436f     /* sqrt(2*log2(e)); acc = (1/tau)*log2e*s */
#define LN2F 0.6931471805599453f

#if __has_builtin(__builtin_amdgcn_exp2f)
#define EXP2F(x) __builtin_amdgcn_exp2f(x)
#else
#define EXP2F(x) exp2f(x)
#endif

typedef __bf16 bf16x8 __attribute__((ext_vector_type(8)));
typedef __bf16 bf16x4v __attribute__((ext_vector_type(4)));
typedef float f32x4 __attribute__((ext_vector_type(4)));
typedef int i32x4 __attribute__((ext_vector_type(4)));
typedef int i32x8 __attribute__((ext_vector_type(8)));
typedef unsigned char uchar;

typedef const __attribute__((address_space(1))) void* gptr_t;
typedef __attribute__((address_space(3))) void* lptr_t;

// ======== legacy 128x128 bf16 GEMM core (proj1/proj2 only) ================
__device__ __forceinline__ void stage_slab(const __bf16* g, int row0, int kelem,
                                           __bf16* lds, int w, int l) {
#pragma unroll
  for (int t = 0; t < 2; ++t) {
    int chunk = w * 2 + t;
    int r = chunk * 16 + (l >> 2);
    int c = l & 3;
    int src = c ^ (r & 3);
    const __bf16* ga = g + (size_t)(row0 + r) * KDIM + kelem + src * 8;
    __bf16* la = lds + chunk * 512;
    __builtin_amdgcn_global_load_lds((gptr_t)ga, (lptr_t)la, 16, 0, 0);
  }
}

__device__ __forceinline__ bf16x8 read_frag(const __bf16* lds, int rowbase,
                                            int tile, int l) {
  int r = rowbase + tile * 16 + (l & 15);
  int q = l >> 4;
  int blk = q ^ (r & 3);
  return *(const bf16x8*)(lds + r * 32 + blk * 8);
}

__device__ __forceinline__ void gemm_tile_core(const __bf16* A, int arow0,
                                               const __bf16* B, int brow0,
                                               __bf16* As, __bf16* Bs,
                                               f32x4 (&acc)[4][4], int w, int l) {
  const int warow = (w >> 1) * 64;
  const int wbrow = (w & 1) * 64;
#pragma unroll
  for (int ks = 0; ks < KDIM / BK; ++ks) {
    __syncthreads();
    stage_slab(A, arow0, ks * BK, As, w, l);
    stage_slab(B, brow0, ks * BK, Bs, w, l);
    __syncthreads();
    bf16x8 aF[4], bF[4];
#pragma unroll
    for (int mi = 0; mi < 4; ++mi) aF[mi] = read_frag(As, warow, mi, l);
#pragma unroll
    for (int ni = 0; ni < 4; ++ni) bF[ni] = read_frag(Bs, wbrow, ni, l);
#pragma unroll
    for (int mi = 0; mi < 4; ++mi)
#pragma unroll
      for (int ni = 0; ni < 4; ++ni)
        acc[mi][ni] = __builtin_amdgcn_mfma_f32_16x16x32_bf16(
            aF[mi], bF[ni], acc[mi][ni], 0, 0, 0);
  }
}

// ---------------------------------------------------------------------------
// one launch: cast z1, z2, W1, W2 to bf16 (float4 granules)
__global__ void cast_all_kernel(const float* __restrict__ z1,
                                const float* __restrict__ z2,
                                const float* __restrict__ W1,
                                const float* __restrict__ W2,
                                __bf16* __restrict__ Zb,
                                __bf16* __restrict__ W1b,
                                __bf16* __restrict__ W2b) {
  const int n4z = NROWS * KDIM / 4;  // 786432
  const int n4w = KDIM * KDIM / 4;   // 16384
  int i = blockIdx.x * blockDim.x + threadIdx.x;
  const float* src;
  __bf16* dst;
  int j;
  if (i < n4z) {
    src = z1; dst = Zb; j = i;
  } else if (i < 2 * n4z) {
    src = z2; dst = Zb + (size_t)NROWS * KDIM; j = i - n4z;
  } else if (i < 2 * n4z + n4w) {
    src = W1; dst = W1b; j = i - 2 * n4z;
  } else if (i < 2 * n4z + 2 * n4w) {
    src = W2; dst = W2b; j = i - 2 * n4z - n4w;
  } else {
    return;
  }
  float4 v = *(const float4*)(src + (size_t)j * 4);
  bf16x4v o;
  o[0] = (__bf16)v.x; o[1] = (__bf16)v.y; o[2] = (__bf16)v.z; o[3] = (__bf16)v.w;
  *(bf16x4v*)(dst + (size_t)j * 4) = o;
}

// T = ELU(Z @ W1^T + b1), stored bf16
__global__ __launch_bounds__(256, 2) void proj1_kernel(
    const __bf16* __restrict__ Zb, const __bf16* __restrict__ W1b,
    const float* __restrict__ b1, __bf16* __restrict__ Tb) {
  __shared__ __align__(16) __bf16 As[BM * BK];
  __shared__ __align__(16) __bf16 Bs[BN * BK];
  int w = threadIdx.x >> 6, l = threadIdx.x & 63;
  int i0 = blockIdx.x * BM, j0 = blockIdx.y * BN;
  int warow = (w >> 1) * 64, wbrow = (w & 1) * 64;
  f32x4 acc[4][4] = {};
  gemm_tile_core(Zb, i0, W1b, j0, As, Bs, acc, w, l);
  float bias[4];
#pragma unroll
  for (int ni = 0; ni < 4; ++ni) bias[ni] = b1[j0 + wbrow + ni * 16 + (l & 15)];
#pragma unroll
  for (int mi = 0; mi < 4; ++mi)
#pragma unroll
    for (int ni = 0; ni < 4; ++ni)
#pragma unroll
      for (int v = 0; v < 4; ++v) {
        int row = i0 + warow + mi * 16 + (l >> 4) * 4 + v;
        int col = j0 + wbrow + ni * 16 + (l & 15);
        float x = acc[mi][ni][v] + bias[ni];
        x = x > 0.f ? x : (EXP2F(x * LOG2E) - 1.f);  // ELU
        Tb[(size_t)row * KDIM + col] = (__bf16)x;
      }
}

// H = T @ W2^T + b2 (fp32), plus per-row sum of squares via atomics
__global__ __launch_bounds__(256, 2) void proj2_kernel(
    const __bf16* __restrict__ Tb, const __bf16* __restrict__ W2b,
    const float* __restrict__ b2, float* __restrict__ H,
    float* __restrict__ SS) {
  __shared__ __align__(16) __bf16 As[BM * BK];
  __shared__ __align__(16) __bf16 Bs[BN * BK];
  int w = threadIdx.x >> 6, l = threadIdx.x & 63;
  int i0 = blockIdx.x * BM, j0 = blockIdx.y * BN;
  int warow = (w >> 1) * 64, wbrow = (w & 1) * 64;
  f32x4 acc[4][4] = {};
  gemm_tile_core(Tb, i0, W2b, j0, As, Bs, acc, w, l);
  float bias[4];
#pragma unroll
  for (int ni = 0; ni < 4; ++ni) bias[ni] = b2[j0 + wbrow + ni * 16 + (l & 15)];
  float ss[4][4] = {};
#pragma unroll
  for (int mi = 0; mi < 4; ++mi)
#pragma unroll
    for (int ni = 0; ni < 4; ++ni)
#pragma unroll
      for (int v = 0; v < 4; ++v) {
        int row = i0 + warow + mi * 16 + (l >> 4) * 4 + v;
        int col = j0 + wbrow + ni * 16 + (l & 15);
        float x = acc[mi][ni][v] + bias[ni];
        H[(size_t)row * KDIM + col] = x;
        ss[mi][v] += x * x;
      }
#pragma unroll
  for (int mi = 0; mi < 4; ++mi)
#pragma unroll
    for (int v = 0; v < 4; ++v) {
      float x = ss[mi][v];
      x += __shfl_xor(x, 1, 64);
      x += __shfl_xor(x, 2, 64);
      x += __shfl_xor(x, 4, 64);
      x += __shfl_xor(x, 8, 64);
      if ((l & 15) == 0)
        atomicAdd(&SS[i0 + warow + mi * 16 + (l >> 4) * 4 + v], x);
    }
}

// pack 4 floats -> 4 fp8 e4m3 bytes
__device__ __forceinline__ unsigned int pack4_fp8(float a, float b, float c,
                                                  float d) {
#if __has_builtin(__builtin_amdgcn_cvt_pk_fp8_f32)
  int v = 0;
  v = __builtin_amdgcn_cvt_pk_fp8_f32(a, b, v, false);
  v = __builtin_amdgcn_cvt_pk_fp8_f32(c, d, v, true);
  return (unsigned int)v;
#else
  __hip_fp8_e4m3 qa(a), qb(b), qc(c), qd(d);
  return (unsigned int)qa.__x | ((unsigned int)qb.__x << 8) |
         ((unsigned int)qc.__x << 16) | ((unsigned int)qd.__x << 24);
#endif
}

// Nq = fp8(H * rsqrt(SS[row]) * SIMSCALE) — 8 elements per thread.
// SIMSCALE folds the (1/tau)*log2(e) exponent scale into the data:
// dot(Nq_i, Nq_j) = 2.8854 * cos_ij, so exp2(acc) = exp(cos/tau).
__global__ void norm_kernel(const float* __restrict__ H,
                            const float* __restrict__ SS,
                            uchar* __restrict__ Nq) {
  int i = blockIdx.x * blockDim.x + threadIdx.x;
  size_t idx = (size_t)i * 8;
  if (idx >= (size_t)TWO_N * KDIM) return;
  int row = (int)(idx >> 8);
  float inv = rsqrtf(SS[row]) * SIMSCALE;
  float4 h0 = *(const float4*)(H + idx);
  float4 h1 = *(const float4*)(H + idx + 4);
  uint2 o;
  o.x = pack4_fp8(h0.x * inv, h0.y * inv, h0.z * inv, h0.w * inv);
  o.y = pack4_fp8(h1.x * inv, h1.y * inv, h1.z * inv, h1.w * inv);
  *(uint2*)(Nq + idx) = o;
}

// ======== R8 sim kernel (MX-scaled fp8, high-occupancy, no spill) ==========
// grid = 768 1D blocks (exactly 3/CU, all co-resident). chunk = blockIdx&7
// (XCD-pinned j-range), itile = blockIdx>>3 (256 A-rows). 4 waves x (64 rows
// x 64 cols). aF 64 VGPRs; acc[4] live per nj step (full-K per nj); jt-level
// LDS double buffer 2x16KB, ONE barrier per jt, stage(jt+1) issued after
// barrier(jt), drains at barrier(jt+1) under 32 MFMAs + exp epilogue.
// launch_bounds(256,3): ~170-reg cap — fits the ~130 this kernel needs
// (R7's (256,4) => 128-cap => aF spilled to scratch => 1.5GB fetch).
__global__ __launch_bounds__(256, 3) void sim_kernel(
    const uchar* __restrict__ Nq, float* __restrict__ Rlow,
    float* __restrict__ Rhigh, float* __restrict__ Dsame,
    float* __restrict__ Dcross) {
  __shared__ __align__(16) uchar Bs[2][BJS * KDIM];  // 2 x 16KB
  int tid = threadIdx.x;
  int w = tid >> 6, l = tid & 63;
  int q = l >> 4;
  int b = blockIdx.x;
  int chunk = b & 7;           // XCD id under round-robin dispatch
  int i0 = (b >> 3) * BMS;
  int jbase = chunk * JCHUNK;
  int warow = w * 64;          // this wave owns rows [warow, warow+64)

  // stage full 64-row x 256B tile jt into buffer bi; source-side XOR
  // swizzle: LDS slot c of row r holds global 16B-block c ^ (r&15).
  auto stage = [&](int jt, int bi) {
    int j0 = jbase + jt * BJS;
#pragma unroll
    for (int t = 0; t < 4; ++t) {
      int ch = w * 4 + t;            // wave-uniform chunk 0..15 (1KB each)
      int r = ch * 4 + (l >> 4);     // row 0..63 (4 rows per chunk)
      int c = l & 15;                // dest 16B-block slot
      int src = c ^ (r & 15);        // global k-block landing in slot c
      const uchar* ga = Nq + (size_t)(j0 + r) * KDIM + src * 16;
      uchar* la = Bs[bi] + ch * 1024;  // wave-uniform base
      __builtin_amdgcn_global_load_lds((gptr_t)ga, (lptr_t)la, 16, 0, 0);
    }
  };

  // ---- A fragments in registers: aF[mi][hf], 8 x i32x8 = 64 VGPRs ----
  // f8f6f4 16x16x128 A layout: lane holds row (l&15), k = q*32 + 0..31.
  i32x8 aF[4][2];
#pragma unroll
  for (int mi = 0; mi < 4; ++mi) {
    const uchar* ap =
        Nq + (size_t)(i0 + warow + mi * 16 + (l & 15)) * KDIM + q * 32;
#pragma unroll
    for (int hf = 0; hf < 2; ++hf)
      aF[mi][hf] = *(const i32x8*)(ap + hf * 128);
  }

  float rs[4][4] = {};  // running row sums (per mi, per v)

  stage(0, 0);  // prologue

  for (int jt = 0; jt < JTILES_S; ++jt) {
    int bi = jt & 1;
    __syncthreads();                       // stage(jt) done; prev readers done
    if (jt + 1 < JTILES_S) stage(jt + 1, bi ^ 1);  // drains at NEXT barrier

    int j0 = jbase + jt * BJS;
    // diagonal hits this wave's 64-row band only when col-tile aligns with it
    bool dsame = (j0 == i0 + warow);
    bool dcross = (j0 == i0 + warow + NROWS);

#pragma unroll
    for (int nj = 0; nj < 4; ++nj) {
      int row = nj * 16 + (l & 15);
      const uchar* base = Bs[bi] + row * KDIM;
      f32x4 acc[4] = {};
#pragma unroll
      for (int hf = 0; hf < 2; ++hf) {
        int kb = hf * 8 + 2 * q;                 // even global block index
        i32x4 lo = *(const i32x4*)(base + ((kb ^ (row & 15)) << 4));
        i32x4 hi = *(const i32x4*)(base + (((kb + 1) ^ (row & 15)) << 4));
        i32x8 bF = __builtin_shufflevector(lo, hi, 0, 1, 2, 3, 4, 5, 6, 7);
#pragma unroll
        for (int mi = 0; mi < 4; ++mi)
          acc[mi] = __builtin_amdgcn_mfma_scale_f32_16x16x128_f8f6f4(
              aF[mi][hf], bF, acc[mi], 0, 0, 0, 0x7F7F7F7F, 0, 0x7F7F7F7F);
      }
      // epilogue for this nj: acc = s/tau*log2(e); exp2 directly
#pragma unroll
      for (int mi = 0; mi < 4; ++mi)
#pragma unroll
        for (int v = 0; v < 4; ++v)
          rs[mi][v] += EXP2F(acc[mi][v]);

      if (dsame | dcross) {       // wave-uniform, 2 of 48 jt iterations
        float* D = dsame ? Dsame : Dcross;
#pragma unroll
        for (int mi = 0; mi < 4; ++mi)
#pragma unroll
          for (int v = 0; v < 4; ++v) {
            int li = mi * 16 + q * 4 + v;     // within wave's 64 rows
            int lj = nj * 16 + (l & 15);      // within tile's 64 cols
            if (li == lj) D[i0 + warow + li] = acc[mi][v];
          }
      }
    }
  }

  // cross-lane (16-wide) reduce, one atomicAdd per row per wave
  float* R = (chunk >= NCHUNK / 2) ? Rhigh : Rlow;
#pragma unroll
  for (int mi = 0; mi < 4; ++mi)
#pragma unroll
    for (int v = 0; v < 4; ++v) {
      float x = rs[mi][v];
      x += __shfl_xor(x, 1, 64);
      x += __shfl_xor(x, 2, 64);
      x += __shfl_xor(x, 4, 64);
      x += __shfl_xor(x, 8, 64);
      if ((l & 15) == 0)
        atomicAdd(&R[i0 + warow + mi * 16 + q * 4 + v], x);
    }
}

// Dsame/Dcross hold acc = (1/tau)*log2e * s. exp(s/tau) = exp2(acc);
// -2*s = -ln2 * acc.  48 blocks x 256 threads = 12288 rows exactly.
__global__ void finalize1_kernel(const float* __restrict__ Rlow,
                                 const float* __restrict__ Rhigh,
                                 const float* __restrict__ Dsame,
                                 const float* __restrict__ Dcross,
                                 float* __restrict__ partial) {
  __shared__ float red[256];
  int k = blockIdx.x * 256 + threadIdx.x;
  float d1 = Rlow[k] + Rhigh[k] - EXP2F(Dsame[k]);
  float d2 = Rhigh[NROWS + k] + Rlow[NROWS + k] - EXP2F(Dsame[NROWS + k]);
  float acc = 0.5f * (logf(d1) + logf(d2)) - LN2F * Dcross[k];
  red[threadIdx.x] = acc;
  __syncthreads();
  for (int s = 128; s > 0; s >>= 1) {
    if (threadIdx.x < s) red[threadIdx.x] += red[threadIdx.x + s];
    __syncthreads();
  }
  if (threadIdx.x == 0) partial[blockIdx.x] = red[0];
}

__global__ void finalize2_kernel(const float* __restrict__ partial,
                                 float* __restrict__ out) {
  float x = (threadIdx.x < FB) ? partial[threadIdx.x] : 0.f;
#pragma unroll
  for (int s = 32; s > 0; s >>= 1) x += __shfl_down(x, s, 64);
  if (threadIdx.x == 0) out[0] = x / (float)NROWS;
}

// ---------------------------------------------------------------------------
extern "C" void kernel_launch(void* const* d_in, const int* in_sizes, int n_in,
                              void* d_out, int out_size, void* d_ws,
                              size_t ws_size, hipStream_t stream) {
  const float* z1 = (const float*)d_in[0];
  const float* z2 = (const float*)d_in[1];
  const float* W1 = (const float*)d_in[2];
  const float* b1 = (const float*)d_in[3];
  const float* W2 = (const float*)d_in[4];
  const float* b2 = (const float*)d_in[5];
  float* out = (float*)d_out;

  char* ws = (char*)d_ws;
  size_t off = 0;
  auto alloc = [&](size_t bytes) -> void* {
    void* p = ws + off;
    off += (bytes + 255) & ~(size_t)255;
    return p;
  };
  __bf16* Zb   = (__bf16*)alloc((size_t)TWO_N * KDIM * 2); // reused as Nq
  __bf16* W1b  = (__bf16*)alloc((size_t)KDIM * KDIM * 2);
  __bf16* W2b  = (__bf16*)alloc((size_t)KDIM * KDIM * 2);
  __bf16* Tb   = (__bf16*)alloc((size_t)TWO_N * KDIM * 2);
  float*  H    = (float*)alloc((size_t)TWO_N * KDIM * 4);
  float*  SS   = (float*)alloc((size_t)TWO_N * 4);
  float*  Rlow = (float*)alloc((size_t)TWO_N * 4);
  float*  Rhigh= (float*)alloc((size_t)TWO_N * 4);
  float*  Dsame= (float*)alloc((size_t)TWO_N * 4);
  float*  Dcross=(float*)alloc((size_t)NROWS * 4);
  float*  partial=(float*)alloc((size_t)FB * 4);
  uchar*  Nq = (uchar*)Zb;  // Zb dead after proj1; fp8 fits in its footprint

  hipMemsetAsync(SS, 0, (size_t)TWO_N * 4, stream);
  hipMemsetAsync(Rlow, 0, (size_t)TWO_N * 4, stream);
  hipMemsetAsync(Rhigh, 0, (size_t)TWO_N * 4, stream);

  int n4z = NROWS * KDIM / 4;   // 786432
  int n4w = KDIM * KDIM / 4;    // 16384
  int n4all = 2 * n4z + 2 * n4w;
  cast_all_kernel<<<(n4all + 255) / 256, 256, 0, stream>>>(z1, z2, W1, W2, Zb,
                                                           W1b, W2b);

  proj1_kernel<<<dim3(TWO_N / BM, KDIM / BN), 256, 0, stream>>>(Zb, W1b, b1, Tb);
  proj2_kernel<<<dim3(TWO_N / BM, KDIM / BN), 256, 0, stream>>>(Tb, W2b, b2, H, SS);

  int n8n = TWO_N * KDIM / 8;   // 786432
  norm_kernel<<<(n8n + 255) / 256, 256, 0, stream>>>(H, SS, Nq);

  sim_kernel<<<(TWO_N / BMS) * NCHUNK, 256, 0, stream>>>(Nq, Rlow, Rhigh,
                                                         Dsame, Dcross);
  finalize1_kernel<<<FB, 256, 0, stream>>>(Rlow, Rhigh, Dsame, Dcross, partial);
  finalize2_kernel<<<1, 64, 0, stream>>>(partial, out);
}